// Round 1
// baseline (121.063 us; speedup 1.0000x reference)
//
#include <hip/hip_runtime.h>

// ChamferLoss: prediction [B,N,3] f32, target [B,M,3] f32 -> scalar f32.
// cham_x = mean_{b,n} min_m max(||x-y||^2, 0); cham_y symmetric; out = sum.
// Strategy: d2 = ||x||^2 + (||y||^2 - 2 x.y). Track min_m of the paren term
// (3 FMA + 1 min per pair), add ||x||^2 and clamp at the end (max(.,0) is
// monotone, so clamp-after-min == min-of-clamped).

#define BLOCK 256
#define RPT 8      // rows per thread
#define MC  256    // target points per LDS chunk

__global__ __launch_bounds__(256) void init_min_kernel(unsigned int* __restrict__ buf, int n) {
    int i = blockIdx.x * blockDim.x + threadIdx.x;
    if (i < n) buf[i] = 0x7f800000u;  // +inf bits
}

// One direction: for each row of X [B,N,3], partial min over an MC-chunk of
// Y [B,M,3]; combine chunks via atomicMin on float-as-uint (values >= 0).
__global__ __launch_bounds__(BLOCK) void chamfer_min_kernel(
    const float* __restrict__ X,        // [B, NX, 3]
    const float* __restrict__ Y,        // [B, NY, 3]
    unsigned int* __restrict__ rowmin,  // [B * NX]
    int NX, int NY) {
    __shared__ float4 ldsY[MC];

    const int b  = blockIdx.z;
    const int mc = blockIdx.y;

    // Stage Y chunk into LDS as (y.x, y.y, y.z, ||y||^2).
    for (int p = threadIdx.x; p < MC; p += BLOCK) {
        const float* yp = Y + ((size_t)b * NY + (size_t)mc * MC + p) * 3;
        float yx = yp[0], yy = yp[1], yz = yp[2];
        ldsY[p] = make_float4(yx, yy, yz, yx * yx + yy * yy + yz * yz);
    }
    __syncthreads();

    // Each thread owns RPT rows (strided by BLOCK within the row tile).
    const int row0 = blockIdx.x * (BLOCK * RPT);
    float qx[RPT], qy[RPT], qz[RPT], x2[RPT], best[RPT];
#pragma unroll
    for (int r = 0; r < RPT; ++r) {
        int row = row0 + r * BLOCK + threadIdx.x;
        const float* xp = X + ((size_t)b * NX + row) * 3;
        float px = xp[0], py = xp[1], pz = xp[2];
        qx[r] = -2.0f * px;
        qy[r] = -2.0f * py;
        qz[r] = -2.0f * pz;
        x2[r] = px * px + py * py + pz * pz;
        best[r] = 3.0e38f;
    }

    // Main loop: LDS read is wave-uniform (broadcast, conflict-free);
    // per m: 1 ds_read_b128 + RPT * (3 fma + 1 min).
#pragma unroll 4
    for (int m = 0; m < MC; ++m) {
        float4 T = ldsY[m];
#pragma unroll
        for (int r = 0; r < RPT; ++r) {
            float cand = fmaf(qx[r], T.x, fmaf(qy[r], T.y, fmaf(qz[r], T.z, T.w)));
            best[r] = fminf(best[r], cand);
        }
    }

#pragma unroll
    for (int r = 0; r < RPT; ++r) {
        int row = row0 + r * BLOCK + threadIdx.x;
        float v = fmaxf(best[r] + x2[r], 0.0f);
        atomicMin(&rowmin[(size_t)b * NX + row], __float_as_uint(v));
    }
}

__global__ __launch_bounds__(1024) void chamfer_reduce_kernel(
    const unsigned int* __restrict__ rowmin,  // B*N
    const unsigned int* __restrict__ colmin,  // B*M
    float* __restrict__ out, int BN, int BM) {
    double v = 0.0;
    for (int i = threadIdx.x; i < BN; i += 1024)
        v += (double)__uint_as_float(rowmin[i]) / (double)BN;
    for (int i = threadIdx.x; i < BM; i += 1024)
        v += (double)__uint_as_float(colmin[i]) / (double)BM;

    // wave reduce (64-wide), then cross-wave via LDS
    for (int off = 32; off > 0; off >>= 1) v += __shfl_down(v, off);
    __shared__ double sh[16];
    int lane = threadIdx.x & 63, wid = threadIdx.x >> 6;
    if (lane == 0) sh[wid] = v;
    __syncthreads();
    if (threadIdx.x == 0) {
        double s = 0.0;
        for (int w = 0; w < 16; ++w) s += sh[w];
        out[0] = (float)s;
    }
}

extern "C" void kernel_launch(void* const* d_in, const int* in_sizes, int n_in,
                              void* d_out, int out_size, void* d_ws, size_t ws_size,
                              hipStream_t stream) {
    const float* pred = (const float*)d_in[0];  // [B, N, 3]
    const float* targ = (const float*)d_in[1];  // [B, M, 3]
    float* out = (float*)d_out;

    const int B = 4, N = 8192, M = 8192;

    unsigned int* rowmin = (unsigned int*)d_ws;        // B*N
    unsigned int* colmin = rowmin + (size_t)B * N;     // B*M

    int tot = B * (N + M);
    init_min_kernel<<<(tot + 255) / 256, 256, 0, stream>>>(rowmin, tot);

    // pred -> targ direction (min over target for each prediction row)
    dim3 g1(N / (BLOCK * RPT), M / MC, B);
    chamfer_min_kernel<<<g1, BLOCK, 0, stream>>>(pred, targ, rowmin, N, M);

    // targ -> pred direction
    dim3 g2(M / (BLOCK * RPT), N / MC, B);
    chamfer_min_kernel<<<g2, BLOCK, 0, stream>>>(targ, pred, colmin, M, N);

    chamfer_reduce_kernel<<<1, 1024, 0, stream>>>(rowmin, colmin, out, B * N, B * M);
}

// Round 2
// 112.609 us; speedup vs baseline: 1.0751x; 1.0751x over previous
//
#include <hip/hip_runtime.h>

// ChamferLoss: prediction [B,N,3] f32, target [B,M,3] f32 -> scalar f32.
// d2 = ||x||^2 + (||y||^2 - 2 x.y); per pair track min of (||y||^2 - 2 x.y)
// (3 FMA + 1 min), fold +||x||^2 and clamp into the per-chunk partial write
// (max(.,0) is monotone so clamp commutes with the later chunk-min).
// v2: no global atomics, no init kernel. Per-chunk partial mins -> ws,
// parallel chunk-min+sum reduce, deterministic final combine.

#define BLOCK 256
#define RPT 8      // rows per thread (keeps VALU:LDS = 16:12 cyc/m, VALU-bound)
#define MC  256    // target points per LDS chunk

__global__ __launch_bounds__(BLOCK) void chamfer_partial_min(
    const float* __restrict__ X,        // [B, NX, 3]
    const float* __restrict__ Y,        // [B, NY, 3]
    float* __restrict__ partial,        // [B, NCH, NX], NCH = gridDim.y
    int NX, int NY) {
    __shared__ float4 ldsY[MC];

    const int b   = blockIdx.z;
    const int mc  = blockIdx.y;
    const int NCH = gridDim.y;

    // Stage Y chunk into LDS as (y.x, y.y, y.z, ||y||^2).
    for (int p = threadIdx.x; p < MC; p += BLOCK) {
        const float* yp = Y + ((size_t)b * NY + (size_t)mc * MC + p) * 3;
        float yx = yp[0], yy = yp[1], yz = yp[2];
        ldsY[p] = make_float4(yx, yy, yz, yx * yx + yy * yy + yz * yz);
    }
    __syncthreads();

    const int row0 = blockIdx.x * (BLOCK * RPT);
    float qx[RPT], qy[RPT], qz[RPT], x2[RPT], best[RPT];
#pragma unroll
    for (int r = 0; r < RPT; ++r) {
        int row = row0 + r * BLOCK + threadIdx.x;
        const float* xp = X + ((size_t)b * NX + row) * 3;
        float px = xp[0], py = xp[1], pz = xp[2];
        qx[r] = -2.0f * px;
        qy[r] = -2.0f * py;
        qz[r] = -2.0f * pz;
        x2[r] = px * px + py * py + pz * pz;
        best[r] = 3.0e38f;
    }

    // Main loop: LDS read is wave-uniform broadcast (conflict-free);
    // per m: 1 ds_read_b128 + RPT * (3 fma + 1 min).
#pragma unroll 8
    for (int m = 0; m < MC; ++m) {
        float4 T = ldsY[m];
#pragma unroll
        for (int r = 0; r < RPT; ++r) {
            float cand = fmaf(qx[r], T.x, fmaf(qy[r], T.y, fmaf(qz[r], T.z, T.w)));
            best[r] = fminf(best[r], cand);
        }
    }

    // Coalesced partial write (lane -> consecutive row).
#pragma unroll
    for (int r = 0; r < RPT; ++r) {
        int row = row0 + r * BLOCK + threadIdx.x;
        partial[((size_t)b * NCH + mc) * NX + row] = fmaxf(best[r] + x2[r], 0.0f);
    }
}

// Each block: 256 rows; min over NCH chunk partials, then block-sum (double).
__global__ __launch_bounds__(256) void chamfer_reduce_rows(
    const float* __restrict__ pA,   // [B, NCH, N]
    const float* __restrict__ pB,   // [B, NCH, M]
    double* __restrict__ blocksum,  // [nblkA + nblkB]
    int N, int M, int B, int NCH) {
    const int j = blockIdx.x;
    const int nblkA = (B * N) / 256;

    const float* src;
    int rows, g0;
    if (j < nblkA) { src = pA; rows = N; g0 = j * 256; }
    else           { src = pB; rows = M; g0 = (j - nblkA) * 256; }

    const int g = g0 + threadIdx.x;     // N,M multiples of 256 -> same b per block
    const int b = g / rows, r = g % rows;

    float v = 3.0e38f;
    for (int c = 0; c < NCH; ++c)
        v = fminf(v, src[((size_t)b * NCH + c) * rows + r]);

    double d = (double)v;
    for (int off = 32; off > 0; off >>= 1) d += __shfl_down(d, off);
    __shared__ double sh[4];
    const int lane = threadIdx.x & 63, wid = threadIdx.x >> 6;
    if (lane == 0) sh[wid] = d;
    __syncthreads();
    if (threadIdx.x == 0)
        blocksum[j] = sh[0] + sh[1] + sh[2] + sh[3];
}

__global__ __launch_bounds__(256) void chamfer_final(
    const double* __restrict__ blocksum, float* __restrict__ out,
    int nblkA, int nblkTot, double invBN, double invBM) {
    const int t = threadIdx.x;
    double d = 0.0;
    if (t < nblkTot)
        d = blocksum[t] * (t < nblkA ? invBN : invBM);
    for (int off = 32; off > 0; off >>= 1) d += __shfl_down(d, off);
    __shared__ double sh[4];
    const int lane = t & 63, wid = t >> 6;
    if (lane == 0) sh[wid] = d;
    __syncthreads();
    if (t == 0) out[0] = (float)(sh[0] + sh[1] + sh[2] + sh[3]);
}

extern "C" void kernel_launch(void* const* d_in, const int* in_sizes, int n_in,
                              void* d_out, int out_size, void* d_ws, size_t ws_size,
                              hipStream_t stream) {
    const float* pred = (const float*)d_in[0];  // [B, N, 3]
    const float* targ = (const float*)d_in[1];  // [B, M, 3]
    float* out = (float*)d_out;

    const int B = 4, N = 8192, M = 8192;
    const int NCH1 = M / MC;   // 32 chunks for direction pred->targ
    const int NCH2 = N / MC;   // 32 chunks for direction targ->pred

    float* pA = (float*)d_ws;                              // B*NCH1*N floats (4 MB)
    float* pB = pA + (size_t)B * NCH1 * N;                 // B*NCH2*M floats (4 MB)
    double* blocksum = (double*)(pB + (size_t)B * NCH2 * M);

    // pred -> targ: min over target for each prediction row
    dim3 g1(N / (BLOCK * RPT), NCH1, B);
    chamfer_partial_min<<<g1, BLOCK, 0, stream>>>(pred, targ, pA, N, M);

    // targ -> pred
    dim3 g2(M / (BLOCK * RPT), NCH2, B);
    chamfer_partial_min<<<g2, BLOCK, 0, stream>>>(targ, pred, pB, M, N);

    const int nblkA = (B * N) / 256;            // 128
    const int nblkTot = nblkA + (B * M) / 256;  // 256
    chamfer_reduce_rows<<<nblkTot, 256, 0, stream>>>(pA, pB, blocksum, N, M, B, NCH1);

    chamfer_final<<<1, 256, 0, stream>>>(blocksum, out, nblkA, nblkTot,
                                         1.0 / ((double)B * N), 1.0 / ((double)B * M));
}

// Round 3
// 102.275 us; speedup vs baseline: 1.1837x; 1.1010x over previous
//
#include <hip/hip_runtime.h>

// ChamferLoss: prediction [B,N,3] f32, target [B,M,3] f32 -> scalar f32.
// d2 = ||x||^2 + (||y||^2 - 2 x.y); per pair track min of (||y||^2 - 2 x.y)
// using 3 FMA per point + 1 v_min3 per 2 points (3.5 VALU-op/pair); fold
// +||x||^2 and clamp into the per-chunk partial write (max(.,0) monotone).
// v3: both directions fused into ONE dispatch; reduce+final fused via
// f64 atomicAdd + ticket counter (zeroed by the min kernel, stream-ordered).

#define BLOCK 256
#define RPT   8      // rows per thread
#define MC    512    // target points per LDS chunk (8 KB)
#define NPTS  8192   // N == M
#define NCH   (NPTS / MC)   // 16 chunks
#define NB    4      // batch

__global__ __launch_bounds__(BLOCK) void chamfer_min_fused(
    const float* __restrict__ pred, const float* __restrict__ targ,
    float* __restrict__ pA,          // [B, NCH, N] partial mins, dir pred->targ
    float* __restrict__ pB,          // [B, NCH, M] partial mins, dir targ->pred
    double* __restrict__ acc, unsigned int* __restrict__ counter) {
    // Zero the reduce kernel's accumulator/counter (this kernel fully
    // completes before the reduce kernel starts — stream order).
    if (blockIdx.x == 0 && blockIdx.y == 0 && blockIdx.z == 0 && threadIdx.x == 0) {
        *acc = 0.0;
        *counter = 0u;
    }

    const int z   = blockIdx.z;       // 0..2B-1: dir = z>>2, b = z&3
    const int dir = z >> 2, b = z & (NB - 1);
    const float* X = dir ? targ : pred;
    const float* Y = dir ? pred : targ;
    float* partial = dir ? pB : pA;

    __shared__ float4 ldsY[MC];
    const int mc = blockIdx.y;

    // Stage Y chunk as (y.x, y.y, y.z, ||y||^2).
    for (int p = threadIdx.x; p < MC; p += BLOCK) {
        const float* yp = Y + ((size_t)b * NPTS + (size_t)mc * MC + p) * 3;
        float yx = yp[0], yy = yp[1], yz = yp[2];
        ldsY[p] = make_float4(yx, yy, yz, fmaf(yx, yx, fmaf(yy, yy, yz * yz)));
    }
    __syncthreads();

    const int row0 = blockIdx.x * (BLOCK * RPT);
    float qx[RPT], qy[RPT], qz[RPT], x2[RPT], best[RPT];
#pragma unroll
    for (int r = 0; r < RPT; ++r) {
        int row = row0 + r * BLOCK + threadIdx.x;
        const float* xp = X + ((size_t)b * NPTS + row) * 3;
        float px = xp[0], py = xp[1], pz = xp[2];
        qx[r] = -2.0f * px;
        qy[r] = -2.0f * py;
        qz[r] = -2.0f * pz;
        x2[r] = fmaf(px, px, fmaf(py, py, pz * pz));
        best[r] = 3.0e38f;
    }

    // Main loop: 2 points per step; LDS reads are wave-uniform broadcasts
    // (conflict-free). Per 2 points per row: 6 FMA + 1 min3.
#pragma unroll 4
    for (int m = 0; m < MC; m += 2) {
        float4 T0 = ldsY[m];
        float4 T1 = ldsY[m + 1];
#pragma unroll
        for (int r = 0; r < RPT; ++r) {
            float c0 = fmaf(qx[r], T0.x, fmaf(qy[r], T0.y, fmaf(qz[r], T0.z, T0.w)));
            float c1 = fmaf(qx[r], T1.x, fmaf(qy[r], T1.y, fmaf(qz[r], T1.z, T1.w)));
            best[r] = fminf(fminf(best[r], c0), c1);   // -> v_min3_f32
        }
    }

    // Coalesced per-chunk partial write (clamp + ||x||^2 folded in).
#pragma unroll
    for (int r = 0; r < RPT; ++r) {
        int row = row0 + r * BLOCK + threadIdx.x;
        partial[((size_t)b * NCH + mc) * NPTS + row] = fmaxf(best[r] + x2[r], 0.0f);
    }
}

// 256 blocks x 256 threads: one row per thread; min over NCH chunk partials,
// block-sum in double, atomicAdd into acc; last block writes the scalar out.
__global__ __launch_bounds__(256) void chamfer_reduce(
    const float* __restrict__ pA, const float* __restrict__ pB,
    double* __restrict__ acc, unsigned int* __restrict__ counter,
    float* __restrict__ out) {
    const int g = blockIdx.x * 256 + threadIdx.x;   // 0 .. 2*B*NPTS-1
    const int half = NB * NPTS;                     // 32768 rows per direction
    const float* src = (g < half) ? pA : pB;
    const int gg = g & (half - 1);
    const int b = gg >> 13, r = gg & (NPTS - 1);

    float v = 3.0e38f;
#pragma unroll
    for (int c = 0; c < NCH; ++c)
        v = fminf(v, src[((size_t)b * NCH + c) * NPTS + r]);

    double d = (double)v;
    for (int off = 32; off > 0; off >>= 1) d += __shfl_down(d, off);
    __shared__ double sh[4];
    const int lane = threadIdx.x & 63, wid = threadIdx.x >> 6;
    if (lane == 0) sh[wid] = d;
    __syncthreads();

    if (threadIdx.x == 0) {
        double blocktotal = sh[0] + sh[1] + sh[2] + sh[3];
        atomicAdd(acc, blocktotal);
        __threadfence();
        unsigned int ticket = atomicAdd(counter, 1u);
        if (ticket == gridDim.x - 1) {
            __threadfence();
            double s = atomicAdd(acc, 0.0);   // atomic read at coherent point
            // both directions divide by B*NPTS = 32768
            out[0] = (float)(s / (double)(NB * NPTS));
        }
    }
}

extern "C" void kernel_launch(void* const* d_in, const int* in_sizes, int n_in,
                              void* d_out, int out_size, void* d_ws, size_t ws_size,
                              hipStream_t stream) {
    const float* pred = (const float*)d_in[0];  // [B, N, 3]
    const float* targ = (const float*)d_in[1];  // [B, M, 3]
    float* out = (float*)d_out;

    float* pA = (float*)d_ws;                               // 2 MB
    float* pB = pA + (size_t)NB * NCH * NPTS;               // 2 MB
    double* acc = (double*)(pB + (size_t)NB * NCH * NPTS);
    unsigned int* counter = (unsigned int*)(acc + 1);

    // Both directions in one dispatch: grid.z = 2*B (dir, batch).
    dim3 g1(NPTS / (BLOCK * RPT), NCH, 2 * NB);             // (4, 16, 8) = 512 blocks
    chamfer_min_fused<<<g1, BLOCK, 0, stream>>>(pred, targ, pA, pB, acc, counter);

    const int nblk = 2 * NB * NPTS / 256;                   // 256
    chamfer_reduce<<<nblk, 256, 0, stream>>>(pA, pB, acc, counter, out);
}